// Round 2
// baseline (2822.292 us; speedup 1.0000x reference)
//
#include <hip/hip_runtime.h>
#include <math.h>

#define NEG_ATT 0.2f
#define NEG 0.01f

static __device__ __forceinline__ float lrelu(float x, float s) { return x > 0.f ? x : s * x; }

// ---------------- CSR build ----------------
__global__ void zero_int_kernel(int* __restrict__ p, int n) {
  int i = blockIdx.x * blockDim.x + threadIdx.x;
  if (i < n) p[i] = 0;
}

__global__ void hist_kernel(const int* __restrict__ dst, int* __restrict__ cnt, int E, int N) {
  int i = blockIdx.x * blockDim.x + threadIdx.x;
  int tot = E + N;
  if (i >= tot) return;
  int d = (i < E) ? dst[i] : (i - E);
  atomicAdd(&cnt[d], 1);
}

// single-block exclusive scan over n counts -> rowptr[0..n], cursor[0..n-1]
__global__ void scan_kernel(const int* __restrict__ cnt, int* __restrict__ rowptr,
                            int* __restrict__ cursor, int n) {
  __shared__ int tmp[1024];
  __shared__ int carry_s;
  int t = threadIdx.x;
  if (t == 0) carry_s = 0;
  __syncthreads();
  for (int base = 0; base < n; base += 1024) {
    int i = base + t;
    int v = (i < n) ? cnt[i] : 0;
    tmp[t] = v;
    __syncthreads();
    #pragma unroll
    for (int off = 1; off < 1024; off <<= 1) {
      int add = (t >= off) ? tmp[t - off] : 0;
      __syncthreads();
      tmp[t] += add;
      __syncthreads();
    }
    int incl = tmp[t];
    int carry = carry_s;
    if (i < n) { int e = carry + incl - v; rowptr[i] = e; cursor[i] = e; }
    __syncthreads();
    if (t == 1023) carry_s = carry + incl;
    __syncthreads();
  }
  if (t == 0) rowptr[n] = carry_s;
}

__global__ void fill_kernel(const int* __restrict__ src, const int* __restrict__ dst,
                            int* __restrict__ cursor, int* __restrict__ colsrc, int E, int N) {
  int i = blockIdx.x * blockDim.x + threadIdx.x;
  int tot = E + N;
  if (i >= tot) return;
  int d, s;
  if (i < E) { d = dst[i]; s = src[i]; } else { d = i - E; s = i - E; }
  int pos = atomicAdd(&cursor[d], 1);
  colsrc[pos] = s;
}

// ---------------- fp32 tiled GEMM: C[M,64*gx] = act(A[M,K] @ B[K, 64*gx] + bias) ----
// A: lda stride; B: ldb stride (pointer pre-offset to column base); C: ldc stride.
// 64x64 tile, 256 threads, 4x4 per thread. act: 0=none, 1=leaky(0.01)
__global__ __launch_bounds__(256) void gemm_bias_act(
    const float* __restrict__ A, const float* __restrict__ B,
    const float* __restrict__ bias, float* __restrict__ C,
    int M, int K, int lda, int ldb, int ldc, int act) {
  __shared__ float As[16][68];
  __shared__ float Bs[16][68];
  int tid = threadIdx.x;
  int tx = tid & 15, ty = tid >> 4;
  int row0 = blockIdx.y * 64, col0 = blockIdx.x * 64;
  float acc[4][4] = {{0.f}};
  for (int k0 = 0; k0 < K; k0 += 16) {
    #pragma unroll
    for (int l = 0; l < 4; ++l) {
      int idx = tid + l * 256;
      int m = idx >> 4, kk = idx & 15;
      int r = row0 + m;
      As[kk][m] = (r < M) ? A[(size_t)r * lda + (k0 + kk)] : 0.f;
    }
    #pragma unroll
    for (int l = 0; l < 4; ++l) {
      int idx = tid + l * 256;
      int kk = idx >> 6, nn = idx & 63;
      Bs[kk][nn] = B[(size_t)(k0 + kk) * ldb + (col0 + nn)];
    }
    __syncthreads();
    #pragma unroll
    for (int kk = 0; kk < 16; ++kk) {
      float4 av = *(const float4*)&As[kk][ty * 4];
      float4 bv = *(const float4*)&Bs[kk][tx * 4];
      float a0[4] = {av.x, av.y, av.z, av.w};
      float b0[4] = {bv.x, bv.y, bv.z, bv.w};
      #pragma unroll
      for (int i = 0; i < 4; ++i)
        #pragma unroll
        for (int j = 0; j < 4; ++j)
          acc[i][j] = fmaf(a0[i], b0[j], acc[i][j]);
    }
    __syncthreads();
  }
  #pragma unroll
  for (int i = 0; i < 4; ++i) {
    int r = row0 + ty * 4 + i;
    if (r >= M) continue;
    #pragma unroll
    for (int j = 0; j < 4; ++j) {
      int c = col0 + tx * 4 + j;
      float v = acc[i][j] + bias[c];
      if (act == 1) v = lrelu(v, NEG);
      C[(size_t)r * ldc + c] = v;
    }
  }
}

// ---------------- GATv2 aggregation, one head, C=256 channels ----------------
// xl/xr compact [N,256]. out written at out + node*out_stride + out_off.
// block = 256 threads = 4 waves; wave = one node; lane = 4 contiguous channels.
__global__ __launch_bounds__(256) void gat_agg(
    const float* __restrict__ xl, const float* __restrict__ xr,
    const int* __restrict__ rowptr, const int* __restrict__ colsrc,
    const float* __restrict__ att, const float* __restrict__ bias,
    float* __restrict__ out, int out_stride, int out_off, int n, int do_elu) {
  int wv = threadIdx.x >> 6, ln = threadIdx.x & 63;
  int d = blockIdx.x * 4 + wv;
  if (d >= n) return;
  int c0 = ln * 4;
  const float4 attv = *(const float4*)(att + c0);
  const float4 xrv = *(const float4*)(xr + (size_t)d * 256 + c0);
  float m = -INFINITY, l = 0.f;
  float ax = 0.f, ay = 0.f, az = 0.f, aw = 0.f;
  int beg = rowptr[d], end = rowptr[d + 1];
  for (int j = beg; j < end; ++j) {
    int s = colsrc[j];
    float4 xlv = *(const float4*)(xl + (size_t)s * 256 + c0);
    float p = lrelu(xlv.x + xrv.x, NEG_ATT) * attv.x
            + lrelu(xlv.y + xrv.y, NEG_ATT) * attv.y
            + lrelu(xlv.z + xrv.z, NEG_ATT) * attv.z
            + lrelu(xlv.w + xrv.w, NEG_ATT) * attv.w;
    #pragma unroll
    for (int off = 32; off >= 1; off >>= 1) p += __shfl_xor(p, off);
    float nm = fmaxf(m, p);
    float scl = __expf(m - nm);   // first iter: exp(-inf)=0
    float w = __expf(p - nm);
    l = l * scl + w;
    ax = fmaf(w, xlv.x, ax * scl);
    ay = fmaf(w, xlv.y, ay * scl);
    az = fmaf(w, xlv.z, az * scl);
    aw = fmaf(w, xlv.w, aw * scl);
    m = nm;
  }
  float inv = 1.f / l;
  const float4 bv = *(const float4*)(bias + c0);
  float4 o;
  o.x = ax * inv + bv.x;
  o.y = ay * inv + bv.y;
  o.z = az * inv + bv.z;
  o.w = aw * inv + bv.w;
  if (do_elu) {
    o.x = o.x > 0.f ? o.x : expm1f(o.x);
    o.y = o.y > 0.f ? o.y : expm1f(o.y);
    o.z = o.z > 0.f ? o.z : expm1f(o.z);
    o.w = o.w > 0.f ? o.w : expm1f(o.w);
  }
  *(float4*)(out + (size_t)d * out_stride + out_off + c0) = o;
}

// ---------------- final: logits = (leaky(h3,0.01)+h) @ W_out + b_out ----------------
__global__ __launch_bounds__(256) void final_logits(
    const float* __restrict__ h3, const float* __restrict__ h,
    const float* __restrict__ Wout, const float* __restrict__ bout,
    float* __restrict__ out, int n) {
  int wv = threadIdx.x >> 6, ln = threadIdx.x & 63;
  int node = blockIdx.x * 4 + wv;
  if (node >= n) return;
  int c0 = ln * 4;
  float4 a = *(const float4*)(h3 + (size_t)node * 256 + c0);
  float4 b = *(const float4*)(h + (size_t)node * 256 + c0);
  float4 w = *(const float4*)(Wout + c0);
  float vx = lrelu(a.x, NEG) + b.x;
  float vy = lrelu(a.y, NEG) + b.y;
  float vz = lrelu(a.z, NEG) + b.z;
  float vw = lrelu(a.w, NEG) + b.w;
  float v = vx * w.x + vy * w.y + vz * w.z + vw * w.w;
  #pragma unroll
  for (int off = 32; off >= 1; off >>= 1) v += __shfl_xor(v, off);
  if (ln == 0) out[node] = v + bout[0];
}

extern "C" void kernel_launch(void* const* d_in, const int* in_sizes, int n_in,
                              void* d_out, int out_size, void* d_ws, size_t ws_size,
                              hipStream_t stream) {
  const float* x    = (const float*)d_in[0];
  const int*   src  = (const int*)d_in[1];
  const int*   dst  = (const int*)d_in[2];
  const float* W_in = (const float*)d_in[3];
  const float* b_in = (const float*)d_in[4];
  const float* Wl1 = (const float*)d_in[5];  const float* bl1 = (const float*)d_in[6];
  const float* Wr1 = (const float*)d_in[7];  const float* br1 = (const float*)d_in[8];
  const float* att1 = (const float*)d_in[9]; const float* bias1 = (const float*)d_in[10];
  const float* Wl2 = (const float*)d_in[11]; const float* bl2 = (const float*)d_in[12];
  const float* Wr2 = (const float*)d_in[13]; const float* br2 = (const float*)d_in[14];
  const float* att2 = (const float*)d_in[15]; const float* bias2 = (const float*)d_in[16];
  const float* Wl3 = (const float*)d_in[17]; const float* bl3 = (const float*)d_in[18];
  const float* Wr3 = (const float*)d_in[19]; const float* br3 = (const float*)d_in[20];
  const float* att3 = (const float*)d_in[21]; const float* bias3 = (const float*)d_in[22];
  const float* W_out = (const float*)d_in[23]; const float* b_out = (const float*)d_in[24];

  const int N = in_sizes[0] / 64;
  const int E = in_sizes[1];
  float* out = (float*)d_out;

  // ---- workspace layout (floats). Peak alloc ~227 MB ----
  float* ws   = (float*)d_ws;
  float* h    = ws;                          // N*256   (persists to end)
  float* buf1 = h + (size_t)N * 256;         // N*1024  (h1; later h3 in first N*256)
  float* buf2 = buf1 + (size_t)N * 1024;     // N*1024  (h2)
  float* s1   = buf2 + (size_t)N * 1024;     // N*256   (per-head xl)
  float* s2   = s1 + (size_t)N * 256;        // N*256   (per-head xr)
  int* cnt    = (int*)(s2 + (size_t)N * 256);
  int* cursor = cnt + N;
  int* rowptr = cursor + N;                  // N+1
  int* colsrc = rowptr + N + 1;              // E+N

  const int tot = E + N;
  // CSR build (by dst, self loops appended)
  zero_int_kernel<<<(N + 255) / 256, 256, 0, stream>>>(cnt, N);
  hist_kernel<<<(tot + 255) / 256, 256, 0, stream>>>(dst, cnt, E, N);
  scan_kernel<<<1, 1024, 0, stream>>>(cnt, rowptr, cursor, N);
  fill_kernel<<<(tot + 255) / 256, 256, 0, stream>>>(src, dst, cursor, colsrc, E, N);

  dim3 blk(256);
  int gy = (N + 63) / 64;
  dim3 g4(4, gy);               // 256 output columns
  int gagg = (N + 3) / 4;

  // h = leaky(x @ W_in + b_in)   [K=64]
  gemm_bias_act<<<g4, blk, 0, stream>>>(x, W_in, b_in, h, N, 64, 64, 256, 256, 1);

  // ---- layer 1: in=h [N,256], out=buf1 [N,1024], 4 heads ----
  for (int hd = 0; hd < 4; ++hd) {
    gemm_bias_act<<<g4, blk, 0, stream>>>(h, Wl1 + hd * 256, bl1 + hd * 256, s1,
                                          N, 256, 256, 1024, 256, 0);
    gemm_bias_act<<<g4, blk, 0, stream>>>(h, Wr1 + hd * 256, br1 + hd * 256, s2,
                                          N, 256, 256, 1024, 256, 0);
    gat_agg<<<gagg, blk, 0, stream>>>(s1, s2, rowptr, colsrc, att1 + hd * 256,
                                      bias1 + hd * 256, buf1, 1024, hd * 256, N, 1);
  }
  // ---- layer 2: in=buf1 [N,1024], out=buf2 [N,1024], 4 heads ----
  for (int hd = 0; hd < 4; ++hd) {
    gemm_bias_act<<<g4, blk, 0, stream>>>(buf1, Wl2 + hd * 256, bl2 + hd * 256, s1,
                                          N, 1024, 1024, 1024, 256, 0);
    gemm_bias_act<<<g4, blk, 0, stream>>>(buf1, Wr2 + hd * 256, br2 + hd * 256, s2,
                                          N, 1024, 1024, 1024, 256, 0);
    gat_agg<<<gagg, blk, 0, stream>>>(s1, s2, rowptr, colsrc, att2 + hd * 256,
                                      bias2 + hd * 256, buf2, 1024, hd * 256, N, 1);
  }
  // ---- layer 3: in=buf2 [N,1024], out=h3 (reuse buf1 first N*256), 1 head ----
  float* h3 = buf1;
  gemm_bias_act<<<g4, blk, 0, stream>>>(buf2, Wl3, bl3, s1, N, 1024, 1024, 256, 256, 0);
  gemm_bias_act<<<g4, blk, 0, stream>>>(buf2, Wr3, br3, s2, N, 1024, 1024, 256, 256, 0);
  gat_agg<<<gagg, blk, 0, stream>>>(s1, s2, rowptr, colsrc, att3, bias3,
                                    h3, 256, 0, N, 0);
  // logits
  final_logits<<<gagg, blk, 0, stream>>>(h3, h, W_out, b_out, out, N);
}

// Round 3
// 941.117 us; speedup vs baseline: 2.9989x; 2.9989x over previous
//
#include <hip/hip_runtime.h>
#include <math.h>

#define NEG_ATT 0.2f
#define NEG 0.01f

typedef __attribute__((ext_vector_type(8))) short short8;
typedef __attribute__((ext_vector_type(4))) float f32x4;

static __device__ __forceinline__ float lrelu(float x, float s) { return x > 0.f ? x : s * x; }
static __device__ __forceinline__ float b2f(unsigned short u) {
  union { unsigned int i; float f; } v; v.i = (unsigned int)u << 16; return v.f;
}
static __device__ __forceinline__ unsigned short f2b(float f) {
  union { float f; unsigned int i; } v; v.f = f;
  unsigned int r = (v.i + 0x7fffu + ((v.i >> 16) & 1u)) >> 16;
  return (unsigned short)r;
}

// ---------------- CSR build ----------------
__global__ void zero_int_kernel(int* __restrict__ p, int n) {
  int i = blockIdx.x * blockDim.x + threadIdx.x;
  if (i < n) p[i] = 0;
}

__global__ void hist_kernel(const int* __restrict__ dst, int* __restrict__ cnt, int E, int N) {
  int i = blockIdx.x * blockDim.x + threadIdx.x;
  int tot = E + N;
  if (i >= tot) return;
  int d = (i < E) ? dst[i] : (i - E);
  atomicAdd(&cnt[d], 1);
}

__global__ void scan_kernel(const int* __restrict__ cnt, int* __restrict__ rowptr,
                            int* __restrict__ cursor, int n) {
  __shared__ int tmp[1024];
  __shared__ int carry_s;
  int t = threadIdx.x;
  if (t == 0) carry_s = 0;
  __syncthreads();
  for (int base = 0; base < n; base += 1024) {
    int i = base + t;
    int v = (i < n) ? cnt[i] : 0;
    tmp[t] = v;
    __syncthreads();
    #pragma unroll
    for (int off = 1; off < 1024; off <<= 1) {
      int add = (t >= off) ? tmp[t - off] : 0;
      __syncthreads();
      tmp[t] += add;
      __syncthreads();
    }
    int incl = tmp[t];
    int carry = carry_s;
    if (i < n) { int e = carry + incl - v; rowptr[i] = e; cursor[i] = e; }
    __syncthreads();
    if (t == 1023) carry_s = carry + incl;
    __syncthreads();
  }
  if (t == 0) rowptr[n] = carry_s;
}

__global__ void fill_kernel(const int* __restrict__ src, const int* __restrict__ dst,
                            int* __restrict__ cursor, int* __restrict__ colsrc, int E, int N) {
  int i = blockIdx.x * blockDim.x + threadIdx.x;
  int tot = E + N;
  if (i >= tot) return;
  int d, s;
  if (i < E) { d = dst[i]; s = src[i]; } else { d = i - E; s = i - E; }
  int pos = atomicAdd(&cursor[d], 1);
  colsrc[pos] = s;
}

// ---------------- weight transpose + bf16 convert: W[K][Ncol] f32 -> Wt[Ncol][K] bf16 ----
__global__ __launch_bounds__(256) void transpose_w_bf16(
    const float* __restrict__ W, unsigned short* __restrict__ Wt, int K, int Ncol) {
  __shared__ float t[32][33];
  int n0 = blockIdx.x * 32, k0 = blockIdx.y * 32;
  int tx = threadIdx.x & 31, ty = threadIdx.x >> 5;  // ty 0..7
  #pragma unroll
  for (int i = 0; i < 4; ++i)
    t[ty + i * 8][tx] = W[(size_t)(k0 + ty + i * 8) * Ncol + n0 + tx];
  __syncthreads();
  #pragma unroll
  for (int i = 0; i < 4; ++i)
    Wt[(size_t)(n0 + ty + i * 8) * K + k0 + tx] = f2b(t[tx][ty + i * 8]);
}

__global__ void f2b_kernel(const float* __restrict__ in, unsigned short* __restrict__ out, int n) {
  int i = blockIdx.x * blockDim.x + threadIdx.x;
  if (i < n) out[i] = f2b(in[i]);
}

// ---------------- bf16 MFMA GEMM: C = act(A[M,K]_bf16 @ Wt^T + bias) ----------------
// A row-major [M][K] bf16 (compact). Bt row-major [Ncol][K] bf16 (pre-transposed weight).
// 128x128 tile, 256 thr = 4 waves (2x2 of 64x64), BK=32, mfma 16x16x32.
// Dual output: Cf (fp32, stride ldcf) if non-null; Cb (bf16, stride ldcb) if non-null.
__global__ __launch_bounds__(256) void gemm_mfma(
    const unsigned short* __restrict__ A, const unsigned short* __restrict__ Bt,
    const float* __restrict__ bias, float* __restrict__ Cf, unsigned short* __restrict__ Cb,
    int M, int K, int ldcf, int ldcb, int act) {
  __shared__ __align__(16) unsigned short As[128][40];
  __shared__ __align__(16) unsigned short Bs[128][40];
  int tid = threadIdx.x;
  int wave = tid >> 6, lane = tid & 63;
  int wm = wave >> 1, wn = wave & 1;
  int quad = lane >> 4, l16 = lane & 15;
  int row0 = blockIdx.y * 128, col0 = blockIdx.x * 128;
  f32x4 acc[4][4];
  #pragma unroll
  for (int i = 0; i < 4; ++i)
    #pragma unroll
    for (int j = 0; j < 4; ++j)
      acc[i][j] = (f32x4){0.f, 0.f, 0.f, 0.f};

  for (int k0 = 0; k0 < K; k0 += 32) {
    #pragma unroll
    for (int l = 0; l < 2; ++l) {
      int idx = tid + l * 256;          // 0..511
      int r = idx >> 2, seg = idx & 3;  // row in tile, 16B segment
      int gr = row0 + r;
      uint4 va = make_uint4(0, 0, 0, 0);
      if (gr < M) va = *(const uint4*)(A + (size_t)gr * K + k0 + seg * 8);
      *(uint4*)&As[r][seg * 8] = va;
      uint4 vb = *(const uint4*)(Bt + (size_t)(col0 + r) * K + k0 + seg * 8);
      *(uint4*)&Bs[r][seg * 8] = vb;
    }
    __syncthreads();
    short8 afr[4], bfr[4];
    #pragma unroll
    for (int t = 0; t < 4; ++t) {
      afr[t] = *(const short8*)&As[wm * 64 + t * 16 + l16][quad * 8];
      bfr[t] = *(const short8*)&Bs[wn * 64 + t * 16 + l16][quad * 8];
    }
    #pragma unroll
    for (int mt = 0; mt < 4; ++mt)
      #pragma unroll
      for (int nt = 0; nt < 4; ++nt)
        acc[mt][nt] = __builtin_amdgcn_mfma_f32_16x16x32_bf16(afr[mt], bfr[nt], acc[mt][nt], 0, 0, 0);
    __syncthreads();
  }

  #pragma unroll
  for (int mt = 0; mt < 4; ++mt) {
    #pragma unroll
    for (int r = 0; r < 4; ++r) {
      int row = row0 + wm * 64 + mt * 16 + quad * 4 + r;
      if (row >= M) continue;
      #pragma unroll
      for (int nt = 0; nt < 4; ++nt) {
        int col = col0 + wn * 64 + nt * 16 + l16;
        float v = acc[mt][nt][r] + bias[col];
        if (act == 1) v = lrelu(v, NEG);
        if (Cf) Cf[(size_t)row * ldcf + col] = v;
        if (Cb) Cb[(size_t)row * ldcb + col] = f2b(v);
      }
    }
  }
}

// ---------------- GATv2 aggregation, 4 heads, bf16 in [N,1024], bf16 out, fused ELU ----
// block = node; wave = head; lane = 4 contiguous channels.
__global__ __launch_bounds__(256) void gat_agg_h4(
    const unsigned short* __restrict__ xl, const unsigned short* __restrict__ xr,
    const int* __restrict__ rowptr, const int* __restrict__ colsrc,
    const float* __restrict__ att, const float* __restrict__ bias,
    unsigned short* __restrict__ outb, int n) {
  int d = blockIdx.x;
  if (d >= n) return;
  int hd = threadIdx.x >> 6, ln = threadIdx.x & 63;
  int c0 = ln * 4;
  const float4 attv = *(const float4*)(att + hd * 256 + c0);
  ushort4 xru = *(const ushort4*)(xr + (size_t)d * 1024 + hd * 256 + c0);
  float xr0 = b2f(xru.x), xr1 = b2f(xru.y), xr2 = b2f(xru.z), xr3 = b2f(xru.w);
  float m = -INFINITY, l = 0.f;
  float ax = 0.f, ay = 0.f, az = 0.f, aw = 0.f;
  int beg = rowptr[d], end = rowptr[d + 1];
  for (int j = beg; j < end; ++j) {
    int s = colsrc[j];
    ushort4 xu = *(const ushort4*)(xl + (size_t)s * 1024 + hd * 256 + c0);
    float x0 = b2f(xu.x), x1 = b2f(xu.y), x2 = b2f(xu.z), x3 = b2f(xu.w);
    float p = lrelu(x0 + xr0, NEG_ATT) * attv.x
            + lrelu(x1 + xr1, NEG_ATT) * attv.y
            + lrelu(x2 + xr2, NEG_ATT) * attv.z
            + lrelu(x3 + xr3, NEG_ATT) * attv.w;
    #pragma unroll
    for (int off = 32; off >= 1; off >>= 1) p += __shfl_xor(p, off);
    float nm = fmaxf(m, p);
    float scl = __expf(m - nm);
    float w = __expf(p - nm);
    l = l * scl + w;
    ax = fmaf(w, x0, ax * scl);
    ay = fmaf(w, x1, ay * scl);
    az = fmaf(w, x2, az * scl);
    aw = fmaf(w, x3, aw * scl);
    m = nm;
  }
  float inv = 1.f / l;
  const float4 bv = *(const float4*)(bias + hd * 256 + c0);
  float o0 = ax * inv + bv.x, o1 = ay * inv + bv.y;
  float o2 = az * inv + bv.z, o3 = aw * inv + bv.w;
  o0 = o0 > 0.f ? o0 : expm1f(o0);
  o1 = o1 > 0.f ? o1 : expm1f(o1);
  o2 = o2 > 0.f ? o2 : expm1f(o2);
  o3 = o3 > 0.f ? o3 : expm1f(o3);
  ushort4 ou = make_ushort4(f2b(o0), f2b(o1), f2b(o2), f2b(o3));
  *(ushort4*)(outb + (size_t)d * 1024 + hd * 256 + c0) = ou;
}

// ---------------- GATv2 aggregation, 1 head, bf16 in [N,256], fp32 out, no act ----
__global__ __launch_bounds__(256) void gat_agg_h1(
    const unsigned short* __restrict__ xl, const unsigned short* __restrict__ xr,
    const int* __restrict__ rowptr, const int* __restrict__ colsrc,
    const float* __restrict__ att, const float* __restrict__ bias,
    float* __restrict__ out, int n) {
  int wv = threadIdx.x >> 6, ln = threadIdx.x & 63;
  int d = blockIdx.x * 4 + wv;
  if (d >= n) return;
  int c0 = ln * 4;
  const float4 attv = *(const float4*)(att + c0);
  ushort4 xru = *(const ushort4*)(xr + (size_t)d * 256 + c0);
  float xr0 = b2f(xru.x), xr1 = b2f(xru.y), xr2 = b2f(xru.z), xr3 = b2f(xru.w);
  float m = -INFINITY, l = 0.f;
  float ax = 0.f, ay = 0.f, az = 0.f, aw = 0.f;
  int beg = rowptr[d], end = rowptr[d + 1];
  for (int j = beg; j < end; ++j) {
    int s = colsrc[j];
    ushort4 xu = *(const ushort4*)(xl + (size_t)s * 256 + c0);
    float x0 = b2f(xu.x), x1 = b2f(xu.y), x2 = b2f(xu.z), x3 = b2f(xu.w);
    float p = lrelu(x0 + xr0, NEG_ATT) * attv.x
            + lrelu(x1 + xr1, NEG_ATT) * attv.y
            + lrelu(x2 + xr2, NEG_ATT) * attv.z
            + lrelu(x3 + xr3, NEG_ATT) * attv.w;
    #pragma unroll
    for (int off = 32; off >= 1; off >>= 1) p += __shfl_xor(p, off);
    float nm = fmaxf(m, p);
    float scl = __expf(m - nm);
    float w = __expf(p - nm);
    l = l * scl + w;
    ax = fmaf(w, x0, ax * scl);
    ay = fmaf(w, x1, ay * scl);
    az = fmaf(w, x2, az * scl);
    aw = fmaf(w, x3, aw * scl);
    m = nm;
  }
  float inv = 1.f / l;
  const float4 bv = *(const float4*)(bias + c0);
  float4 o;
  o.x = ax * inv + bv.x;
  o.y = ay * inv + bv.y;
  o.z = az * inv + bv.z;
  o.w = aw * inv + bv.w;
  *(float4*)(out + (size_t)d * 256 + c0) = o;
}

// ---------------- final: logits = (leaky(h3,0.01)+h) @ W_out + b_out ----------------
__global__ __launch_bounds__(256) void final_logits(
    const float* __restrict__ h3, const float* __restrict__ h,
    const float* __restrict__ Wout, const float* __restrict__ bout,
    float* __restrict__ out, int n) {
  int wv = threadIdx.x >> 6, ln = threadIdx.x & 63;
  int node = blockIdx.x * 4 + wv;
  if (node >= n) return;
  int c0 = ln * 4;
  float4 a = *(const float4*)(h3 + (size_t)node * 256 + c0);
  float4 b = *(const float4*)(h + (size_t)node * 256 + c0);
  float4 w = *(const float4*)(Wout + c0);
  float vx = lrelu(a.x, NEG) + b.x;
  float vy = lrelu(a.y, NEG) + b.y;
  float vz = lrelu(a.z, NEG) + b.z;
  float vw = lrelu(a.w, NEG) + b.w;
  float v = vx * w.x + vy * w.y + vz * w.z + vw * w.w;
  #pragma unroll
  for (int off = 32; off >= 1; off >>= 1) v += __shfl_xor(v, off);
  if (ln == 0) out[node] = v + bout[0];
}

extern "C" void kernel_launch(void* const* d_in, const int* in_sizes, int n_in,
                              void* d_out, int out_size, void* d_ws, size_t ws_size,
                              hipStream_t stream) {
  const float* x    = (const float*)d_in[0];
  const int*   src  = (const int*)d_in[1];
  const int*   dst  = (const int*)d_in[2];
  const float* W_in = (const float*)d_in[3];
  const float* b_in = (const float*)d_in[4];
  const float* Wl1 = (const float*)d_in[5];  const float* bl1 = (const float*)d_in[6];
  const float* Wr1 = (const float*)d_in[7];  const float* br1 = (const float*)d_in[8];
  const float* att1 = (const float*)d_in[9]; const float* bias1 = (const float*)d_in[10];
  const float* Wl2 = (const float*)d_in[11]; const float* bl2 = (const float*)d_in[12];
  const float* Wr2 = (const float*)d_in[13]; const float* br2 = (const float*)d_in[14];
  const float* att2 = (const float*)d_in[15]; const float* bias2 = (const float*)d_in[16];
  const float* Wl3 = (const float*)d_in[17]; const float* bl3 = (const float*)d_in[18];
  const float* Wr3 = (const float*)d_in[19]; const float* br3 = (const float*)d_in[20];
  const float* att3 = (const float*)d_in[21]; const float* bias3 = (const float*)d_in[22];
  const float* W_out = (const float*)d_in[23]; const float* b_out = (const float*)d_in[24];

  const int N = in_sizes[0] / 64;
  const int E = in_sizes[1];
  float* out = (float*)d_out;

  // ---- workspace layout. Total ~226 MB ----
  char* p = (char*)d_ws;
  float* h   = (float*)p;            p += (size_t)N * 256 * 4;   // fp32 residual
  float* h3  = (float*)p;            p += (size_t)N * 256 * 4;   // fp32 layer3 out
  unsigned short* xbf  = (unsigned short*)p; p += (size_t)N * 64 * 2;
  unsigned short* hbf  = (unsigned short*)p; p += (size_t)N * 256 * 2;
  unsigned short* h1bf = (unsigned short*)p; p += (size_t)N * 1024 * 2;
  unsigned short* h2bf = (unsigned short*)p; p += (size_t)N * 1024 * 2;
  unsigned short* xlbf = (unsigned short*)p; p += (size_t)N * 1024 * 2;
  unsigned short* xrbf = (unsigned short*)p; p += (size_t)N * 1024 * 2;
  unsigned short* WtIn = (unsigned short*)p; p += (size_t)64 * 256 * 2;
  unsigned short* WtL1 = (unsigned short*)p; p += (size_t)256 * 1024 * 2;
  unsigned short* WtR1 = (unsigned short*)p; p += (size_t)256 * 1024 * 2;
  unsigned short* WtL2 = (unsigned short*)p; p += (size_t)1024 * 1024 * 2;
  unsigned short* WtR2 = (unsigned short*)p; p += (size_t)1024 * 1024 * 2;
  unsigned short* WtL3 = (unsigned short*)p; p += (size_t)1024 * 256 * 2;
  unsigned short* WtR3 = (unsigned short*)p; p += (size_t)1024 * 256 * 2;
  int* cnt    = (int*)p;             p += (size_t)N * 4;
  int* cursor = (int*)p;             p += (size_t)N * 4;
  int* rowptr = (int*)p;             p += (size_t)(N + 1) * 4;
  int* colsrc = (int*)p;

  const int tot = E + N;
  dim3 blk(256);

  // CSR build (by dst, self loops appended)
  zero_int_kernel<<<(N + 255) / 256, blk, 0, stream>>>(cnt, N);
  hist_kernel<<<(tot + 255) / 256, blk, 0, stream>>>(dst, cnt, E, N);
  scan_kernel<<<1, 1024, 0, stream>>>(cnt, rowptr, cursor, N);
  fill_kernel<<<(tot + 255) / 256, blk, 0, stream>>>(src, dst, cursor, colsrc, E, N);

  // weight conversions (W[K][Ncol] -> Wt[Ncol][K] bf16)
  transpose_w_bf16<<<dim3(256 / 32, 64 / 32), blk, 0, stream>>>(W_in, WtIn, 64, 256);
  transpose_w_bf16<<<dim3(1024 / 32, 256 / 32), blk, 0, stream>>>(Wl1, WtL1, 256, 1024);
  transpose_w_bf16<<<dim3(1024 / 32, 256 / 32), blk, 0, stream>>>(Wr1, WtR1, 256, 1024);
  transpose_w_bf16<<<dim3(1024 / 32, 1024 / 32), blk, 0, stream>>>(Wl2, WtL2, 1024, 1024);
  transpose_w_bf16<<<dim3(1024 / 32, 1024 / 32), blk, 0, stream>>>(Wr2, WtR2, 1024, 1024);
  transpose_w_bf16<<<dim3(256 / 32, 1024 / 32), blk, 0, stream>>>(Wl3, WtL3, 1024, 256);
  transpose_w_bf16<<<dim3(256 / 32, 1024 / 32), blk, 0, stream>>>(Wr3, WtR3, 1024, 256);
  f2b_kernel<<<(N * 64 + 255) / 256, blk, 0, stream>>>(x, xbf, N * 64);

  int gy = (N + 127) / 128;
  int gagg4 = N;
  int gagg1 = (N + 3) / 4;

  // h = leaky(x @ W_in + b_in): fp32 h + bf16 hbf
  gemm_mfma<<<dim3(2, gy), blk, 0, stream>>>(xbf, WtIn, b_in, h, hbf, N, 64, 256, 256, 1);

  // layer 1: K=256, Ncol=1024
  gemm_mfma<<<dim3(8, gy), blk, 0, stream>>>(hbf, WtL1, bl1, nullptr, xlbf, N, 256, 0, 1024, 0);
  gemm_mfma<<<dim3(8, gy), blk, 0, stream>>>(hbf, WtR1, br1, nullptr, xrbf, N, 256, 0, 1024, 0);
  gat_agg_h4<<<gagg4, blk, 0, stream>>>(xlbf, xrbf, rowptr, colsrc, att1, bias1, h1bf, N);

  // layer 2: K=1024, Ncol=1024
  gemm_mfma<<<dim3(8, gy), blk, 0, stream>>>(h1bf, WtL2, bl2, nullptr, xlbf, N, 1024, 0, 1024, 0);
  gemm_mfma<<<dim3(8, gy), blk, 0, stream>>>(h1bf, WtR2, br2, nullptr, xrbf, N, 1024, 0, 1024, 0);
  gat_agg_h4<<<gagg4, blk, 0, stream>>>(xlbf, xrbf, rowptr, colsrc, att2, bias2, h2bf, N);

  // layer 3: K=1024, Ncol=256 (compact xl/xr)
  gemm_mfma<<<dim3(2, gy), blk, 0, stream>>>(h2bf, WtL3, bl3, nullptr, xlbf, N, 1024, 0, 256, 0);
  gemm_mfma<<<dim3(2, gy), blk, 0, stream>>>(h2bf, WtR3, br3, nullptr, xrbf, N, 1024, 0, 256, 0);
  gat_agg_h1<<<gagg1, blk, 0, stream>>>(xlbf, xrbf, rowptr, colsrc, att3, bias3, h3, N);

  // logits
  final_logits<<<gagg1, blk, 0, stream>>>(h3, h, W_out, b_out, out, N);
}

// Round 4
// 779.150 us; speedup vs baseline: 3.6223x; 1.2079x over previous
//
#include <hip/hip_runtime.h>
#include <math.h>

#define NEG_ATT 0.2f
#define NEG 0.01f

typedef __attribute__((ext_vector_type(8))) short short8;
typedef __attribute__((ext_vector_type(4))) float f32x4;

static __device__ __forceinline__ float lrelu(float x, float s) { return x > 0.f ? x : s * x; }
static __device__ __forceinline__ unsigned short f2b(float f) {
  union { float f; unsigned int i; } v; v.f = f;
  unsigned int r = (v.i + 0x7fffu + ((v.i >> 16) & 1u)) >> 16;
  return (unsigned short)r;
}
static __device__ __forceinline__ void unpack8(uint4 r, float* x) {
  union { unsigned int u; float f; } t;
  t.u = r.x << 16;          x[0] = t.f;
  t.u = r.x & 0xffff0000u;  x[1] = t.f;
  t.u = r.y << 16;          x[2] = t.f;
  t.u = r.y & 0xffff0000u;  x[3] = t.f;
  t.u = r.z << 16;          x[4] = t.f;
  t.u = r.z & 0xffff0000u;  x[5] = t.f;
  t.u = r.w << 16;          x[6] = t.f;
  t.u = r.w & 0xffff0000u;  x[7] = t.f;
}

// ---------------- CSR build ----------------
__global__ void zero_int_kernel(int* __restrict__ p, int n) {
  int i = blockIdx.x * blockDim.x + threadIdx.x;
  if (i < n) p[i] = 0;
}

__global__ void hist_kernel(const int* __restrict__ dst, int* __restrict__ cnt, int E, int N) {
  int i = blockIdx.x * blockDim.x + threadIdx.x;
  int tot = E + N;
  if (i >= tot) return;
  int d = (i < E) ? dst[i] : (i - E);
  atomicAdd(&cnt[d], 1);
}

// single-block exclusive scan, shfl-based (2 syncs per 1024-chunk instead of 20)
__global__ void scan_kernel(const int* __restrict__ cnt, int* __restrict__ rowptr,
                            int* __restrict__ cursor, int n) {
  __shared__ int wsum[16];
  __shared__ int carry_s;
  int t = threadIdx.x;           // 1024 threads
  int lane = t & 63, wv = t >> 6;
  if (t == 0) carry_s = 0;
  __syncthreads();
  for (int base = 0; base < n; base += 1024) {
    int i = base + t;
    int orig = (i < n) ? cnt[i] : 0;
    int v = orig;
    #pragma unroll
    for (int off = 1; off < 64; off <<= 1) {
      int u = __shfl_up(v, off);
      if (lane >= off) v += u;
    }
    if (lane == 63) wsum[wv] = v;
    __syncthreads();
    if (t < 16) {
      int s = wsum[t];
      #pragma unroll
      for (int off = 1; off < 16; off <<= 1) {
        int u = __shfl_up(s, off);
        if (t >= off) s += u;
      }
      wsum[t] = s;
    }
    __syncthreads();
    int waveoff = (wv > 0) ? wsum[wv - 1] : 0;
    int carry = carry_s;
    int excl = carry + waveoff + v - orig;
    if (i < n) { rowptr[i] = excl; cursor[i] = excl; }
    __syncthreads();
    if (t == 0) carry_s = carry + wsum[15];
    __syncthreads();
  }
  if (t == 0) rowptr[n] = carry_s;
}

__global__ void fill_kernel(const int* __restrict__ src, const int* __restrict__ dst,
                            int* __restrict__ cursor, int* __restrict__ colsrc, int E, int N) {
  int i = blockIdx.x * blockDim.x + threadIdx.x;
  int tot = E + N;
  if (i >= tot) return;
  int d, s;
  if (i < E) { d = dst[i]; s = src[i]; } else { d = i - E; s = i - E; }
  int pos = atomicAdd(&cursor[d], 1);
  colsrc[pos] = s;
}

// ---------------- weight transpose + bf16 convert: W[K][Ncol] f32 -> Wt[Ncol][K] bf16 ----
__global__ __launch_bounds__(256) void transpose_w_bf16(
    const float* __restrict__ W, unsigned short* __restrict__ Wt, int K, int Ncol) {
  __shared__ float t[32][33];
  int n0 = blockIdx.x * 32, k0 = blockIdx.y * 32;
  int tx = threadIdx.x & 31, ty = threadIdx.x >> 5;  // ty 0..7
  #pragma unroll
  for (int i = 0; i < 4; ++i)
    t[ty + i * 8][tx] = W[(size_t)(k0 + ty + i * 8) * Ncol + n0 + tx];
  __syncthreads();
  #pragma unroll
  for (int i = 0; i < 4; ++i)
    Wt[(size_t)(n0 + ty + i * 8) * K + k0 + tx] = f2b(t[tx][ty + i * 8]);
}

__global__ void f2b_kernel(const float* __restrict__ in, unsigned short* __restrict__ out, int n) {
  int i = blockIdx.x * blockDim.x + threadIdx.x;
  if (i < n) out[i] = f2b(in[i]);
}

// ---------------- bf16 MFMA GEMM with register-prefetch pipeline ----------------
// A row-major [M][K] bf16. Bt row-major [Ncol][K] bf16 (Ncol = 128*gridDim.x).
// 128x128 tile, 256 thr = 4 waves (2x2 of 64x64), BK=32, mfma 16x16x32.
// Dual output: Cf (fp32, stride ldcf) if non-null; Cb (bf16, stride ldcb) if non-null.
__global__ __launch_bounds__(256) void gemm_mfma(
    const unsigned short* __restrict__ A, const unsigned short* __restrict__ Bt,
    const float* __restrict__ bias, float* __restrict__ Cf, unsigned short* __restrict__ Cb,
    int M, int K, int ldcf, int ldcb, int act) {
  __shared__ __align__(16) unsigned short As[128][40];
  __shared__ __align__(16) unsigned short Bs[128][40];
  int tid = threadIdx.x;
  int wave = tid >> 6, lane = tid & 63;
  int wm = wave >> 1, wn = wave & 1;
  int quad = lane >> 4, l16 = lane & 15;
  int row0 = blockIdx.y * 128, col0 = blockIdx.x * 128;
  int r0 = tid >> 2, seg0 = tid & 3;          // staging slot l=0 (rows 0..63)
  int r1 = r0 + 64, seg1 = seg0;              // staging slot l=1 (rows 64..127)
  f32x4 acc[4][4];
  #pragma unroll
  for (int i = 0; i < 4; ++i)
    #pragma unroll
    for (int j = 0; j < 4; ++j)
      acc[i][j] = (f32x4){0.f, 0.f, 0.f, 0.f};

  uint4 sa0, sa1, sb0, sb1;
  {
    int gr0 = row0 + r0, gr1 = row0 + r1;
    sa0 = (gr0 < M) ? *(const uint4*)(A + (size_t)gr0 * K + seg0 * 8) : make_uint4(0,0,0,0);
    sa1 = (gr1 < M) ? *(const uint4*)(A + (size_t)gr1 * K + seg1 * 8) : make_uint4(0,0,0,0);
    sb0 = *(const uint4*)(Bt + (size_t)(col0 + r0) * K + seg0 * 8);
    sb1 = *(const uint4*)(Bt + (size_t)(col0 + r1) * K + seg1 * 8);
  }
  for (int k0 = 0; k0 < K; k0 += 32) {
    *(uint4*)&As[r0][seg0 * 8] = sa0;
    *(uint4*)&As[r1][seg1 * 8] = sa1;
    *(uint4*)&Bs[r0][seg0 * 8] = sb0;
    *(uint4*)&Bs[r1][seg1 * 8] = sb1;
    __syncthreads();
    int kn = k0 + 32;
    if (kn < K) {
      int gr0 = row0 + r0, gr1 = row0 + r1;
      sa0 = (gr0 < M) ? *(const uint4*)(A + (size_t)gr0 * K + kn + seg0 * 8) : make_uint4(0,0,0,0);
      sa1 = (gr1 < M) ? *(const uint4*)(A + (size_t)gr1 * K + kn + seg1 * 8) : make_uint4(0,0,0,0);
      sb0 = *(const uint4*)(Bt + (size_t)(col0 + r0) * K + kn + seg0 * 8);
      sb1 = *(const uint4*)(Bt + (size_t)(col0 + r1) * K + kn + seg1 * 8);
    }
    short8 afr[4], bfr[4];
    #pragma unroll
    for (int t = 0; t < 4; ++t) {
      afr[t] = *(const short8*)&As[wm * 64 + t * 16 + l16][quad * 8];
      bfr[t] = *(const short8*)&Bs[wn * 64 + t * 16 + l16][quad * 8];
    }
    #pragma unroll
    for (int mt = 0; mt < 4; ++mt)
      #pragma unroll
      for (int nt = 0; nt < 4; ++nt)
        acc[mt][nt] = __builtin_amdgcn_mfma_f32_16x16x32_bf16(afr[mt], bfr[nt], acc[mt][nt], 0, 0, 0);
    __syncthreads();
  }

  #pragma unroll
  for (int mt = 0; mt < 4; ++mt) {
    #pragma unroll
    for (int r = 0; r < 4; ++r) {
      int row = row0 + wm * 64 + mt * 16 + quad * 4 + r;
      if (row >= M) continue;
      #pragma unroll
      for (int nt = 0; nt < 4; ++nt) {
        int col = col0 + wn * 64 + nt * 16 + l16;
        float v = acc[mt][nt][r] + bias[col];
        if (act == 1) v = lrelu(v, NEG);
        if (Cf) Cf[(size_t)row * ldcf + col] = v;
        if (Cb) Cb[(size_t)row * ldcb + col] = f2b(v);
      }
    }
  }
}

// ---------------- GATv2 aggregation, 4 heads ----------------
// xlr: [n][2048] bf16, xl = cols 0..1023, xr = cols 1024..2047.
// block = node; wave = head; half-wave = one edge; lane = 8 channels.
__global__ __launch_bounds__(256) void gat_agg_h4(
    const unsigned short* __restrict__ xlr,
    const int* __restrict__ rowptr, const int* __restrict__ colsrc,
    const float* __restrict__ att, const float* __restrict__ bias,
    unsigned short* __restrict__ outb, int n) {
  const int S = 2048, XROFF = 1024;
  int d = blockIdx.x;
  if (d >= n) return;
  int hd = threadIdx.x >> 6, ln = threadIdx.x & 63;
  int half = ln >> 5, l32 = ln & 31;
  int c0 = l32 * 8;
  float a[8], a5[8], xr_[8];
  {
    float4 t0 = *(const float4*)(att + hd * 256 + c0);
    float4 t1 = *(const float4*)(att + hd * 256 + c0 + 4);
    a[0]=t0.x; a[1]=t0.y; a[2]=t0.z; a[3]=t0.w;
    a[4]=t1.x; a[5]=t1.y; a[6]=t1.z; a[7]=t1.w;
    #pragma unroll
    for (int c = 0; c < 8; ++c) a5[c] = NEG_ATT * a[c];
    uint4 r = *(const uint4*)(xlr + (size_t)d * S + XROFF + hd * 256 + c0);
    unpack8(r, xr_);
  }
  float m = -1e30f, l = 0.f, acc[8];
  #pragma unroll
  for (int c = 0; c < 8; ++c) acc[c] = 0.f;
  int beg = rowptr[d], end = rowptr[d + 1];
  for (int j = beg; j < end; j += 2) {
    int jj = j + half;
    bool valid = (jj < end);
    int s = colsrc[valid ? jj : j];
    uint4 raw = *(const uint4*)(xlr + (size_t)s * S + hd * 256 + c0);
    float x[8];
    unpack8(raw, x);
    float p = 0.f;
    #pragma unroll
    for (int c = 0; c < 8; ++c) {
      float u = x[c] + xr_[c];
      p = fmaf(u, (u > 0.f ? a[c] : a5[c]), p);
    }
    #pragma unroll
    for (int off = 16; off >= 1; off >>= 1) p += __shfl_xor(p, off);
    if (!valid) p = -1e30f;
    float nm = fmaxf(m, p);
    if (nm > m) {                   // new max: rescale old state
      float scl = __expf(m - nm);
      l *= scl;
      #pragma unroll
      for (int c = 0; c < 8; ++c) acc[c] *= scl;
      m = nm;
    }
    float w = __expf(p - m);
    l += w;
    #pragma unroll
    for (int c = 0; c < 8; ++c) acc[c] = fmaf(w, x[c], acc[c]);
  }
  // merge the two half-wave online-softmax states
  float mo = __shfl_xor(m, 32);
  float lo = __shfl_xor(l, 32);
  float M = fmaxf(m, mo);
  float sl = __expf(m - M);
  float so = __expf(mo - M);
  float L = fmaf(l, sl, lo * so);
  float inv = 1.f / L;
  float4 b0 = *(const float4*)(bias + hd * 256 + c0);
  float4 b1 = *(const float4*)(bias + hd * 256 + c0 + 4);
  float bb[8] = {b0.x, b0.y, b0.z, b0.w, b1.x, b1.y, b1.z, b1.w};
  unsigned int ou[4];
  #pragma unroll
  for (int c = 0; c < 8; ++c) {
    float po = __shfl_xor(acc[c], 32);
    float v = fmaf(acc[c], sl, po * so) * inv + bb[c];
    v = v > 0.f ? v : expm1f(v);     // ELU
    unsigned int bv = (unsigned int)f2b(v);
    if (c & 1) ou[c >> 1] |= bv << 16; else ou[c >> 1] = bv;
  }
  if (half == 0) {
    uint4 o = make_uint4(ou[0], ou[1], ou[2], ou[3]);
    *(uint4*)(outb + (size_t)d * 1024 + hd * 256 + c0) = o;
  }
}

// ---------------- GATv2 aggregation, 1 head, fp32 out, no activation ----------------
// xlr: [n][512] bf16, xl = cols 0..255, xr = cols 256..511.
// block = 4 waves = 4 nodes; half-wave = one edge; lane = 8 channels.
__global__ __launch_bounds__(256) void gat_agg_h1(
    const unsigned short* __restrict__ xlr,
    const int* __restrict__ rowptr, const int* __restrict__ colsrc,
    const float* __restrict__ att, const float* __restrict__ bias,
    float* __restrict__ out, int n) {
  const int S = 512, XROFF = 256;
  int wv = threadIdx.x >> 6, ln = threadIdx.x & 63;
  int d = blockIdx.x * 4 + wv;
  if (d >= n) return;
  int half = ln >> 5, l32 = ln & 31;
  int c0 = l32 * 8;
  float a[8], a5[8], xr_[8];
  {
    float4 t0 = *(const float4*)(att + c0);
    float4 t1 = *(const float4*)(att + c0 + 4);
    a[0]=t0.x; a[1]=t0.y; a[2]=t0.z; a[3]=t0.w;
    a[4]=t1.x; a[5]=t1.y; a[6]=t1.z; a[7]=t1.w;
    #pragma unroll
    for (int c = 0; c < 8; ++c) a5[c] = NEG_ATT * a[c];
    uint4 r = *(const uint4*)(xlr + (size_t)d * S + XROFF + c0);
    unpack8(r, xr_);
  }
  float m = -1e30f, l = 0.f, acc[8];
  #pragma unroll
  for (int c = 0; c < 8; ++c) acc[c] = 0.f;
  int beg = rowptr[d], end = rowptr[d + 1];
  for (int j = beg; j < end; j += 2) {
    int jj = j + half;
    bool valid = (jj < end);
    int s = colsrc[valid ? jj : j];
    uint4 raw = *(const uint4*)(xlr + (size_t)s * S + c0);
    float x[8];
    unpack8(raw, x);
    float p = 0.f;
    #pragma unroll
    for (int c = 0; c < 8; ++c) {
      float u = x[c] + xr_[c];
      p = fmaf(u, (u > 0.f ? a[c] : a5[c]), p);
    }
    #pragma unroll
    for (int off = 16; off >= 1; off >>= 1) p += __shfl_xor(p, off);
    if (!valid) p = -1e30f;
    float nm = fmaxf(m, p);
    if (nm > m) {
      float scl = __expf(m - nm);
      l *= scl;
      #pragma unroll
      for (int c = 0; c < 8; ++c) acc[c] *= scl;
      m = nm;
    }
    float w = __expf(p - m);
    l += w;
    #pragma unroll
    for (int c = 0; c < 8; ++c) acc[c] = fmaf(w, x[c], acc[c]);
  }
  float mo = __shfl_xor(m, 32);
  float lo = __shfl_xor(l, 32);
  float M = fmaxf(m, mo);
  float sl = __expf(m - M);
  float so = __expf(mo - M);
  float L = fmaf(l, sl, lo * so);
  float inv = 1.f / L;
  float4 b0 = *(const float4*)(bias + c0);
  float4 b1 = *(const float4*)(bias + c0 + 4);
  float bb[8] = {b0.x, b0.y, b0.z, b0.w, b1.x, b1.y, b1.z, b1.w};
  float ov[8];
  #pragma unroll
  for (int c = 0; c < 8; ++c) {
    float po = __shfl_xor(acc[c], 32);
    ov[c] = fmaf(acc[c], sl, po * so) * inv + bb[c];
  }
  if (half == 0) {
    float4 o0 = {ov[0], ov[1], ov[2], ov[3]};
    float4 o1 = {ov[4], ov[5], ov[6], ov[7]};
    *(float4*)(out + (size_t)d * 256 + c0) = o0;
    *(float4*)(out + (size_t)d * 256 + c0 + 4) = o1;
  }
}

// ---------------- final: logits = (leaky(h3,0.01)+h) @ W_out + b_out ----------------
__global__ __launch_bounds__(256) void final_logits(
    const float* __restrict__ h3, const float* __restrict__ h,
    const float* __restrict__ Wout, const float* __restrict__ bout,
    float* __restrict__ out, int n) {
  int wv = threadIdx.x >> 6, ln = threadIdx.x & 63;
  int node = blockIdx.x * 4 + wv;
  if (node >= n) return;
  int c0 = ln * 4;
  float4 a = *(const float4*)(h3 + (size_t)node * 256 + c0);
  float4 b = *(const float4*)(h + (size_t)node * 256 + c0);
  float4 w = *(const float4*)(Wout + c0);
  float vx = lrelu(a.x, NEG) + b.x;
  float vy = lrelu(a.y, NEG) + b.y;
  float vz = lrelu(a.z, NEG) + b.z;
  float vw = lrelu(a.w, NEG) + b.w;
  float v = vx * w.x + vy * w.y + vz * w.z + vw * w.w;
  #pragma unroll
  for (int off = 32; off >= 1; off >>= 1) v += __shfl_xor(v, off);
  if (ln == 0) out[node] = v + bout[0];
}

extern "C" void kernel_launch(void* const* d_in, const int* in_sizes, int n_in,
                              void* d_out, int out_size, void* d_ws, size_t ws_size,
                              hipStream_t stream) {
  const float* x    = (const float*)d_in[0];
  const int*   src  = (const int*)d_in[1];
  const int*   dst  = (const int*)d_in[2];
  const float* W_in = (const float*)d_in[3];
  const float* b_in = (const float*)d_in[4];
  const float* Wl1 = (const float*)d_in[5];  const float* bl1 = (const float*)d_in[6];
  const float* Wr1 = (const float*)d_in[7];  const float* br1 = (const float*)d_in[8];
  const float* att1 = (const float*)d_in[9]; const float* bias1 = (const float*)d_in[10];
  const float* Wl2 = (const float*)d_in[11]; const float* bl2 = (const float*)d_in[12];
  const float* Wr2 = (const float*)d_in[13]; const float* br2 = (const float*)d_in[14];
  const float* att2 = (const float*)d_in[15]; const float* bias2 = (const float*)d_in[16];
  const float* Wl3 = (const float*)d_in[17]; const float* bl3 = (const float*)d_in[18];
  const float* Wr3 = (const float*)d_in[19]; const float* br3 = (const float*)d_in[20];
  const float* att3 = (const float*)d_in[21]; const float* bias3 = (const float*)d_in[22];
  const float* W_out = (const float*)d_in[23]; const float* b_out = (const float*)d_in[24];

  const int N = in_sizes[0] / 64;
  const int E = in_sizes[1];
  float* out = (float*)d_out;

  // ---- workspace layout. Total ~225 MB ----
  char* p = (char*)d_ws;
  float* h   = (float*)p;            p += (size_t)N * 256 * 4;   // fp32 residual
  float* h3  = (float*)p;            p += (size_t)N * 256 * 4;   // fp32 layer3 out
  unsigned short* xbf  = (unsigned short*)p; p += (size_t)N * 64 * 2;
  unsigned short* hbf  = (unsigned short*)p; p += (size_t)N * 256 * 2;
  unsigned short* h1bf = (unsigned short*)p; p += (size_t)N * 1024 * 2;
  unsigned short* h2bf = (unsigned short*)p; p += (size_t)N * 1024 * 2;
  unsigned short* xlr  = (unsigned short*)p; p += (size_t)N * 2048 * 2;
  unsigned short* WtIn  = (unsigned short*)p; p += (size_t)256 * 64 * 2;
  unsigned short* WtLR1 = (unsigned short*)p; p += (size_t)2048 * 256 * 2;
  unsigned short* WtLR2 = (unsigned short*)p; p += (size_t)2048 * 1024 * 2;
  unsigned short* WtLR3 = (unsigned short*)p; p += (size_t)512 * 1024 * 2;
  float* bLR1 = (float*)p;           p += (size_t)2048 * 4;
  float* bLR2 = (float*)p;           p += (size_t)2048 * 4;
  float* bLR3 = (float*)p;           p += (size_t)512 * 4;
  int* cnt    = (int*)p;             p += (size_t)N * 4;
  int* cursor = (int*)p;             p += (size_t)N * 4;
  int* rowptr = (int*)p;             p += (size_t)(N + 1) * 4;
  int* colsrc = (int*)p;

  const int tot = E + N;
  dim3 blk(256);

  // CSR build (by dst, self loops appended)
  zero_int_kernel<<<(N + 255) / 256, blk, 0, stream>>>(cnt, N);
  hist_kernel<<<(tot + 255) / 256, blk, 0, stream>>>(dst, cnt, E, N);
  scan_kernel<<<1, 1024, 0, stream>>>(cnt, rowptr, cursor, N);
  fill_kernel<<<(tot + 255) / 256, blk, 0, stream>>>(src, dst, cursor, colsrc, E, N);

  // weight conversions: W[K][Ncol] -> Wt[Ncol][K] bf16, L/R fused along Ncol
  transpose_w_bf16<<<dim3(8, 2), blk, 0, stream>>>(W_in, WtIn, 64, 256);
  transpose_w_bf16<<<dim3(32, 8), blk, 0, stream>>>(Wl1, WtLR1, 256, 1024);
  transpose_w_bf16<<<dim3(32, 8), blk, 0, stream>>>(Wr1, WtLR1 + (size_t)1024 * 256, 256, 1024);
  transpose_w_bf16<<<dim3(32, 32), blk, 0, stream>>>(Wl2, WtLR2, 1024, 1024);
  transpose_w_bf16<<<dim3(32, 32), blk, 0, stream>>>(Wr2, WtLR2 + (size_t)1024 * 1024, 1024, 1024);
  transpose_w_bf16<<<dim3(8, 32), blk, 0, stream>>>(Wl3, WtLR3, 1024, 256);
  transpose_w_bf16<<<dim3(8, 32), blk, 0, stream>>>(Wr3, WtLR3 + (size_t)256 * 1024, 1024, 256);
  f2b_kernel<<<(N * 64 + 255) / 256, blk, 0, stream>>>(x, xbf, N * 64);

  // fused bias vectors
  hipMemcpyAsync(bLR1, bl1, 1024 * 4, hipMemcpyDeviceToDevice, stream);
  hipMemcpyAsync(bLR1 + 1024, br1, 1024 * 4, hipMemcpyDeviceToDevice, stream);
  hipMemcpyAsync(bLR2, bl2, 1024 * 4, hipMemcpyDeviceToDevice, stream);
  hipMemcpyAsync(bLR2 + 1024, br2, 1024 * 4, hipMemcpyDeviceToDevice, stream);
  hipMemcpyAsync(bLR3, bl3, 256 * 4, hipMemcpyDeviceToDevice, stream);
  hipMemcpyAsync(bLR3 + 256, br3, 256 * 4, hipMemcpyDeviceToDevice, stream);

  int gy = (N + 127) / 128;
  int gagg4 = N;
  int gagg1 = (N + 3) / 4;

  // h = leaky(x @ W_in + b_in): fp32 h + bf16 hbf
  gemm_mfma<<<dim3(2, gy), blk, 0, stream>>>(xbf, WtIn, b_in, h, hbf, N, 64, 256, 256, 1);

  // layer 1: K=256, fused L|R -> xlr [N,2048]
  gemm_mfma<<<dim3(16, gy), blk, 0, stream>>>(hbf, WtLR1, bLR1, nullptr, xlr, N, 256, 0, 2048, 0);
  gat_agg_h4<<<gagg4, blk, 0, stream>>>(xlr, rowptr, colsrc, att1, bias1, h1bf, N);

  // layer 2: K=1024, fused L|R -> xlr [N,2048]
  gemm_mfma<<<dim3(16, gy), blk, 0, stream>>>(h1bf, WtLR2, bLR2, nullptr, xlr, N, 1024, 0, 2048, 0);
  gat_agg_h4<<<gagg4, blk, 0, stream>>>(xlr, rowptr, colsrc, att2, bias2, h2bf, N);

  // layer 3: K=1024, fused L|R -> xlr [N,512]
  gemm_mfma<<<dim3(4, gy), blk, 0, stream>>>(h2bf, WtLR3, bLR3, nullptr, xlr, N, 1024, 0, 512, 0);
  gat_agg_h1<<<gagg1, blk, 0, stream>>>(xlr, rowptr, colsrc, att3, bias3, h3, N);

  // logits
  final_logits<<<gagg1, blk, 0, stream>>>(h3, h, W_out, b_out, out, N);
}